// Round 4
// baseline (1821.188 us; speedup 1.0000x reference)
//
#include <hip/hip_runtime.h>

// LiquidNN LTC: B=512, S=512, D=H=128, O=1, UNFOLDS=6, dt=0.1, tau=1.
// 2 waves per batch row (grid=512, block=128, 2 blocks/CU = 1 wave/SIMD).
// Thread t owns output row o=t: FULL 128-MAC dot product per output ->
// no cross-lane shuffle in the main loop.
//
// KEY FIX (round 4): rounds 0-2 all had VGPR_Count (72/148/84) far below the
// weight-register footprint -> the compiler was sinking the loop-invariant
// weight loads INTO the loop, re-reading 32KB/wave/matvec from L2 (128KB f32
// weight set > 32KB L1). That was the ~1166 cyc/phase bottleneck.
// Round-3's volatile-pointer fix didn't compile (HIP_vector_type copy-ctor
// loses volatile). This round: OPAQUE ASM PIN -- after converting each weight
// chunk to f16, pass it through asm volatile("" : "+v"(w)). The compiler
// cannot rematerialize an opaque asm result and cannot sink a volatile asm
// into the loop, so all 32 v8h chunks (128 VGPRs) stay register-resident.
//
// h fp32 in registers (authoritative), f16 copy double-buffered in LDS;
// all lanes read the SAME LDS addresses (broadcast, no bank traffic).

typedef _Float16 v8h __attribute__((ext_vector_type(8)));

#define S_LEN 512
#define HDIM  128
#define NUNF  6
#define DTC   0.1f

__device__ __forceinline__ float fast_tanh(float y) {
    // tanh(y) = 1 - 2/(e^{2y}+1); v_exp/v_rcp based, NaN-free at +-inf
    float u = __expf(2.0f * y);
    return 1.0f - __fdividef(2.0f, u + 1.0f);
}

// 8 f32 -> one v8h (2 float4 loads, vectorized to global_load_dwordx4).
#define LD8(PTR, I) ({                                             \
    float4 _a = (PTR)[2*(I)+0];                                    \
    float4 _b = (PTR)[2*(I)+1];                                    \
    v8h{(_Float16)_a.x,(_Float16)_a.y,(_Float16)_a.z,(_Float16)_a.w, \
        (_Float16)_b.x,(_Float16)_b.y,(_Float16)_b.z,(_Float16)_b.w}; })

// Opaque pin: value becomes an asm output -> cannot be rematerialized,
// volatile -> cannot be sunk into the loop. Forces register residency.
#define PIN(V) asm volatile("" : "+v"(V))

// 8 MACs: one v8h weight chunk vs one v8h vector chunk, 4 acc chains.
#define DOT8(W, X)                                                 \
    a0 = __builtin_amdgcn_fdot2(W.s01, X.s01, a0, false);          \
    a1 = __builtin_amdgcn_fdot2(W.s23, X.s23, a1, false);          \
    a2 = __builtin_amdgcn_fdot2(W.s45, X.s45, a2, false);          \
    a3 = __builtin_amdgcn_fdot2(W.s67, X.s67, a3, false);

// Full 128-length f16 dot: named weight regs W##0..W##15 vs LDS vector at BUF
// (16 broadcast ds_read_b128 -> 16 v8h temps).
#define MATVEC(W, BUF, RES) do {                                   \
    const v8h* _p = reinterpret_cast<const v8h*>(BUF);             \
    v8h x0 = _p[0],  x1 = _p[1],  x2 = _p[2],  x3 = _p[3];         \
    v8h x4 = _p[4],  x5 = _p[5],  x6 = _p[6],  x7 = _p[7];         \
    v8h x8 = _p[8],  x9 = _p[9],  xa = _p[10], xb = _p[11];        \
    v8h xc = _p[12], xd = _p[13], xe = _p[14], xf = _p[15];        \
    float a0 = 0.f, a1 = 0.f, a2 = 0.f, a3 = 0.f;                  \
    DOT8(W##0, x0)  DOT8(W##1, x1)  DOT8(W##2, x2)  DOT8(W##3, x3) \
    DOT8(W##4, x4)  DOT8(W##5, x5)  DOT8(W##6, x6)  DOT8(W##7, x7) \
    DOT8(W##8, x8)  DOT8(W##9, x9)  DOT8(W##10, xa) DOT8(W##11, xb)\
    DOT8(W##12, xc) DOT8(W##13, xd) DOT8(W##14, xe) DOT8(W##15, xf)\
    RES = (a0 + a1) + (a2 + a3);                                   \
} while (0)

__global__ __launch_bounds__(128, 1)
void ltc_kernel(const float* __restrict__ x,
                const float* __restrict__ W_in,
                const float* __restrict__ b_in,
                const float* __restrict__ W_r,
                const float* __restrict__ b_r,
                const float* __restrict__ W_fc,
                const float* __restrict__ b_fc,
                float* __restrict__ out)
{
    const int b   = blockIdx.x;
    const int tid = threadIdx.x;     // 0..127 == output row o

    __shared__ __align__(16) _Float16 hbuf[2][HDIM];
    __shared__ __align__(16) _Float16 xbuf[2][HDIM];
    __shared__ float red[2];

    // ---- one-time: own W_r row + W_in row -> 32 named v8h regs (128 VGPRs) ----
    const float4* wrp = reinterpret_cast<const float4*>(W_r  + (size_t)tid * HDIM);
    const float4* wip = reinterpret_cast<const float4*>(W_in + (size_t)tid * HDIM);
    v8h wr0  = LD8(wrp, 0),  wr1  = LD8(wrp, 1),  wr2  = LD8(wrp, 2),  wr3  = LD8(wrp, 3);
    v8h wr4  = LD8(wrp, 4),  wr5  = LD8(wrp, 5),  wr6  = LD8(wrp, 6),  wr7  = LD8(wrp, 7);
    v8h wr8  = LD8(wrp, 8),  wr9  = LD8(wrp, 9),  wr10 = LD8(wrp, 10), wr11 = LD8(wrp, 11);
    v8h wr12 = LD8(wrp, 12), wr13 = LD8(wrp, 13), wr14 = LD8(wrp, 14), wr15 = LD8(wrp, 15);
    v8h wi0  = LD8(wip, 0),  wi1  = LD8(wip, 1),  wi2  = LD8(wip, 2),  wi3  = LD8(wip, 3);
    v8h wi4  = LD8(wip, 4),  wi5  = LD8(wip, 5),  wi6  = LD8(wip, 6),  wi7  = LD8(wip, 7);
    v8h wi8  = LD8(wip, 8),  wi9  = LD8(wip, 9),  wi10 = LD8(wip, 10), wi11 = LD8(wip, 11);
    v8h wi12 = LD8(wip, 12), wi13 = LD8(wip, 13), wi14 = LD8(wip, 14), wi15 = LD8(wip, 15);
    PIN(wr0);  PIN(wr1);  PIN(wr2);  PIN(wr3);
    PIN(wr4);  PIN(wr5);  PIN(wr6);  PIN(wr7);
    PIN(wr8);  PIN(wr9);  PIN(wr10); PIN(wr11);
    PIN(wr12); PIN(wr13); PIN(wr14); PIN(wr15);
    PIN(wi0);  PIN(wi1);  PIN(wi2);  PIN(wi3);
    PIN(wi4);  PIN(wi5);  PIN(wi6);  PIN(wi7);
    PIN(wi8);  PIN(wi9);  PIN(wi10); PIN(wi11);
    PIN(wi12); PIN(wi13); PIN(wi14); PIN(wi15);

    const float binv = b_in[tid];
    const float brv  = b_r[tid];

    const float* x_row = x + (size_t)b * S_LEN * HDIM;

    // ---- prologue: h = 0, stage x[0] as f16 ----
    xbuf[0][tid] = (_Float16)x_row[tid];
    hbuf[0][tid] = (_Float16)0.0f;
    __syncthreads();

    float h = 0.0f;   // fp32 authoritative h (thread-local output)

#pragma unroll 1
    for (int s = 0; s < S_LEN; ++s) {
        // prefetch next step's x (coalesced 4B/lane; latency hidden by step)
        float xn = 0.0f;
        if (s + 1 < S_LEN)
            xn = x_row[(size_t)(s + 1) * HDIM + tid];

        // ---- input map: independent of h -> covers prev h-write->read latency ----
        float xs;
        MATVEC(wi, &xbuf[s & 1][0], xs);
        const float xin = xs + binv;

        // ---- 6 ODE unfolds ----
#pragma unroll
        for (int u = 0; u < NUNF; ++u) {
            float sr;
            MATVEC(wr, &hbuf[u & 1][0], sr);
            float v = fast_tanh(xin + brv + sr);
            h += DTC * (v - h);                    // tau=1: h += dt*(-h+v)
            hbuf[(u + 1) & 1][tid] = (_Float16)h;
            if (u == 0)  // stage next x mid-step (global load landed by now)
                xbuf[(s + 1) & 1][tid] = (_Float16)xn;
            __syncthreads();
        }
    }

    // ---- epilogue: out[b] = h . W_fc[0,:] + b_fc ----
    float partial = h * W_fc[tid];
#pragma unroll
    for (int d = 1; d < 64; d <<= 1) partial += __shfl_xor(partial, d);
    if ((tid & 63) == 0) red[tid >> 6] = partial;
    __syncthreads();
    if (tid == 0) out[b] = red[0] + red[1] + b_fc[0];
}

extern "C" void kernel_launch(void* const* d_in, const int* in_sizes, int n_in,
                              void* d_out, int out_size, void* d_ws, size_t ws_size,
                              hipStream_t stream) {
    const float* x    = (const float*)d_in[0];
    const float* W_in = (const float*)d_in[1];
    const float* b_in = (const float*)d_in[2];
    const float* W_r  = (const float*)d_in[3];
    const float* b_r  = (const float*)d_in[4];
    const float* W_fc = (const float*)d_in[5];
    const float* b_fc = (const float*)d_in[6];
    float* outp = (float*)d_out;
    (void)in_sizes; (void)n_in; (void)out_size; (void)d_ws; (void)ws_size;
    ltc_kernel<<<dim3(512), dim3(128), 0, stream>>>(x, W_in, b_in, W_r, b_r, W_fc, b_fc, outp);
}

// Round 5
// 1380.776 us; speedup vs baseline: 1.3190x; 1.3190x over previous
//
#include <hip/hip_runtime.h>

// LiquidNN LTC: B=512, S=512, D=H=128, O=1, UNFOLDS=6, dt=0.1, tau=1.
// 2 waves per batch row (grid=512, block=128, 2 blocks/CU = 1 wave/SIMD).
// Thread t owns output row o=t: FULL 128-MAC dot product per output.
//
// ROUND 5: every prior round (VGPR 72/148/84/100) lost the weight-residency
// fight -- the GCN scheduler remat-sinks the weight load+cvt chain into the
// s-loop chasing occupancy the grid can't use, re-reading 32KB/wave/matvec
// from L2 (~1160 cyc/phase, the measured bottleneck). Two fixes it can't dodge:
//  (1) amdgpu_waves_per_eu(1,1): occupancy TARGET = 1 wave/EU -> 512-VGPR
//      budget, pressure-reduction remat has nothing to gain.
//  (2) pins INSIDE the s-loop: asm volatile("":"+v"(w)) each iteration makes
//      every weight chunk a loop-carried VGPR dependency (opaque redefinition)
//      -- remat is no longer a legal substitute, spill+reload of 128 VGPRs
//      per iteration loses to keeping them resident.
// Also: input-map fused into unfold 0 (x-reads issued BEFORE h-reads; xin
// dot2s execute while h-chunks arrive) -> 6 LDS-latency phases/step, not 7.

typedef _Float16 v8h __attribute__((ext_vector_type(8)));

#define S_LEN 512
#define HDIM  128
#define NUNF  6
#define DTC   0.1f

__device__ __forceinline__ float fast_tanh(float y) {
    // tanh(y) = 1 - 2/(e^{2y}+1); v_exp/v_rcp based, NaN-free at +-inf
    float u = __expf(2.0f * y);
    return 1.0f - __fdividef(2.0f, u + 1.0f);
}

// 8 f32 -> one v8h (2 float4 loads, vectorized to global_load_dwordx4).
#define LD8(PTR, I) ({                                             \
    float4 _a = (PTR)[2*(I)+0];                                    \
    float4 _b = (PTR)[2*(I)+1];                                    \
    v8h{(_Float16)_a.x,(_Float16)_a.y,(_Float16)_a.z,(_Float16)_a.w, \
        (_Float16)_b.x,(_Float16)_b.y,(_Float16)_b.z,(_Float16)_b.w}; })

// Opaque in-loop pin: redefines the value each iteration -> loop-carried
// VGPR dependency; emits ZERO instructions.
#define PIN(V) asm volatile("" : "+v"(V))

// 8 MACs: one v8h weight chunk vs one v8h vector chunk, 4 acc chains.
#define DOT8(W, X)                                                 \
    a0 = __builtin_amdgcn_fdot2(W.s01, X.s01, a0, false);          \
    a1 = __builtin_amdgcn_fdot2(W.s23, X.s23, a1, false);          \
    a2 = __builtin_amdgcn_fdot2(W.s45, X.s45, a2, false);          \
    a3 = __builtin_amdgcn_fdot2(W.s67, X.s67, a3, false);

// Full 128-length recurrent dot: wr0..wr15 vs LDS h-vector at BUF
// (16 broadcast ds_read_b128 -> 16 v8h temps, all lanes same address).
#define MATVEC_WR(BUF, RES) do {                                   \
    const v8h* _p = reinterpret_cast<const v8h*>(BUF);             \
    v8h t0=_p[0], t1=_p[1], t2=_p[2],  t3=_p[3];                   \
    v8h t4=_p[4], t5=_p[5], t6=_p[6],  t7=_p[7];                   \
    v8h t8=_p[8], t9=_p[9], ta=_p[10], tb=_p[11];                  \
    v8h tc=_p[12],td=_p[13],te=_p[14], tf=_p[15];                  \
    float a0=0.f, a1=0.f, a2=0.f, a3=0.f;                          \
    DOT8(wr0,t0)  DOT8(wr1,t1)  DOT8(wr2,t2)   DOT8(wr3,t3)        \
    DOT8(wr4,t4)  DOT8(wr5,t5)  DOT8(wr6,t6)   DOT8(wr7,t7)        \
    DOT8(wr8,t8)  DOT8(wr9,t9)  DOT8(wr10,ta)  DOT8(wr11,tb)       \
    DOT8(wr12,tc) DOT8(wr13,td) DOT8(wr14,te)  DOT8(wr15,tf)       \
    RES = (a0+a1)+(a2+a3);                                         \
} while (0)

__global__ __launch_bounds__(128)
__attribute__((amdgpu_waves_per_eu(1, 1)))
void ltc_kernel(const float* __restrict__ x,
                const float* __restrict__ W_in,
                const float* __restrict__ b_in,
                const float* __restrict__ W_r,
                const float* __restrict__ b_r,
                const float* __restrict__ W_fc,
                const float* __restrict__ b_fc,
                float* __restrict__ out)
{
    const int b   = blockIdx.x;
    const int tid = threadIdx.x;     // 0..127 == output row o

    __shared__ __align__(16) _Float16 hbuf[2][HDIM];
    __shared__ __align__(16) _Float16 xbuf[2][HDIM];
    __shared__ float red[2];

    // ---- one-time: own W_r row + W_in row -> 32 named v8h regs (128 VGPRs) ----
    const float4* wrp = reinterpret_cast<const float4*>(W_r  + (size_t)tid * HDIM);
    const float4* wip = reinterpret_cast<const float4*>(W_in + (size_t)tid * HDIM);
    v8h wr0  = LD8(wrp, 0),  wr1  = LD8(wrp, 1),  wr2  = LD8(wrp, 2),  wr3  = LD8(wrp, 3);
    v8h wr4  = LD8(wrp, 4),  wr5  = LD8(wrp, 5),  wr6  = LD8(wrp, 6),  wr7  = LD8(wrp, 7);
    v8h wr8  = LD8(wrp, 8),  wr9  = LD8(wrp, 9),  wr10 = LD8(wrp, 10), wr11 = LD8(wrp, 11);
    v8h wr12 = LD8(wrp, 12), wr13 = LD8(wrp, 13), wr14 = LD8(wrp, 14), wr15 = LD8(wrp, 15);
    v8h wi0  = LD8(wip, 0),  wi1  = LD8(wip, 1),  wi2  = LD8(wip, 2),  wi3  = LD8(wip, 3);
    v8h wi4  = LD8(wip, 4),  wi5  = LD8(wip, 5),  wi6  = LD8(wip, 6),  wi7  = LD8(wip, 7);
    v8h wi8  = LD8(wip, 8),  wi9  = LD8(wip, 9),  wi10 = LD8(wip, 10), wi11 = LD8(wip, 11);
    v8h wi12 = LD8(wip, 12), wi13 = LD8(wip, 13), wi14 = LD8(wip, 14), wi15 = LD8(wip, 15);

    const float binv = b_in[tid];
    const float brv  = b_r[tid];

    const float* x_row = x + (size_t)b * S_LEN * HDIM;

    // ---- prologue: h = 0, stage x[0] as f16 ----
    xbuf[0][tid] = (_Float16)x_row[tid];
    hbuf[0][tid] = (_Float16)0.0f;
    __syncthreads();

    float h = 0.0f;   // fp32 authoritative h (thread-local output)

#pragma unroll 1
    for (int s = 0; s < S_LEN; ++s) {
        // In-loop pins: loop-carried VGPR deps, zero instructions emitted.
        PIN(wr0);  PIN(wr1);  PIN(wr2);  PIN(wr3);
        PIN(wr4);  PIN(wr5);  PIN(wr6);  PIN(wr7);
        PIN(wr8);  PIN(wr9);  PIN(wr10); PIN(wr11);
        PIN(wr12); PIN(wr13); PIN(wr14); PIN(wr15);
        PIN(wi0);  PIN(wi1);  PIN(wi2);  PIN(wi3);
        PIN(wi4);  PIN(wi5);  PIN(wi6);  PIN(wi7);
        PIN(wi8);  PIN(wi9);  PIN(wi10); PIN(wi11);
        PIN(wi12); PIN(wi13); PIN(wi14); PIN(wi15);

        // prefetch next step's x (coalesced 4B/lane; landed before u==3 staging)
        float xn = 0.0f;
        if (s + 1 < S_LEN)
            xn = x_row[(size_t)(s + 1) * HDIM + tid];

        float xb;   // xin + b_r, reused by all 6 unfolds
        // ---- unfold 0, fused with input map: issue x-reads BEFORE h-reads;
        // xin dot2s execute while the h-chunks are still in flight ----
        {
            const v8h* xp = reinterpret_cast<const v8h*>(&xbuf[s & 1][0]);
            const v8h* hp = reinterpret_cast<const v8h*>(&hbuf[0][0]);
            v8h X0=xp[0], X1=xp[1], X2=xp[2],  X3=xp[3];
            v8h X4=xp[4], X5=xp[5], X6=xp[6],  X7=xp[7];
            v8h X8=xp[8], X9=xp[9], Xa=xp[10], Xb=xp[11];
            v8h Xc=xp[12],Xd=xp[13],Xe=xp[14], Xf=xp[15];
            v8h H0=hp[0], H1=hp[1], H2=hp[2],  H3=hp[3];
            v8h H4=hp[4], H5=hp[5], H6=hp[6],  H7=hp[7];
            v8h H8=hp[8], H9=hp[9], Ha=hp[10], Hb=hp[11];
            v8h Hc=hp[12],Hd=hp[13],He=hp[14], Hf=hp[15];
            float a0=0.f, a1=0.f, a2=0.f, a3=0.f;
            DOT8(wi0,X0)  DOT8(wi1,X1)  DOT8(wi2,X2)   DOT8(wi3,X3)
            DOT8(wi4,X4)  DOT8(wi5,X5)  DOT8(wi6,X6)   DOT8(wi7,X7)
            DOT8(wi8,X8)  DOT8(wi9,X9)  DOT8(wi10,Xa)  DOT8(wi11,Xb)
            DOT8(wi12,Xc) DOT8(wi13,Xd) DOT8(wi14,Xe)  DOT8(wi15,Xf)
            xb = (a0+a1)+(a2+a3) + binv + brv;
            a0=0.f; a1=0.f; a2=0.f; a3=0.f;
            DOT8(wr0,H0)  DOT8(wr1,H1)  DOT8(wr2,H2)   DOT8(wr3,H3)
            DOT8(wr4,H4)  DOT8(wr5,H5)  DOT8(wr6,H6)   DOT8(wr7,H7)
            DOT8(wr8,H8)  DOT8(wr9,H9)  DOT8(wr10,Ha)  DOT8(wr11,Hb)
            DOT8(wr12,Hc) DOT8(wr13,Hd) DOT8(wr14,He)  DOT8(wr15,Hf)
            float sr = (a0+a1)+(a2+a3);
            float v  = fast_tanh(xb + sr);
            h += DTC * (v - h);
            hbuf[1][tid] = (_Float16)h;
            __syncthreads();
        }

        // ---- unfolds 1..5 ----
#pragma unroll
        for (int u = 1; u < NUNF; ++u) {
            float sr;
            MATVEC_WR(&hbuf[u & 1][0], sr);
            float v = fast_tanh(xb + sr);
            h += DTC * (v - h);                    // tau=1: h += dt*(-h+v)
            hbuf[(u + 1) & 1][tid] = (_Float16)h;
            if (u == 3)  // stage next x late (global load long landed; next
                xbuf[(s + 1) & 1][tid] = (_Float16)xn;  // read is after u5 barrier)
            __syncthreads();
        }
    }

    // ---- epilogue: out[b] = h . W_fc[0,:] + b_fc ----
    float partial = h * W_fc[tid];
#pragma unroll
    for (int d = 1; d < 64; d <<= 1) partial += __shfl_xor(partial, d);
    if ((tid & 63) == 0) red[tid >> 6] = partial;
    __syncthreads();
    if (tid == 0) out[b] = red[0] + red[1] + b_fc[0];
}

extern "C" void kernel_launch(void* const* d_in, const int* in_sizes, int n_in,
                              void* d_out, int out_size, void* d_ws, size_t ws_size,
                              hipStream_t stream) {
    const float* x    = (const float*)d_in[0];
    const float* W_in = (const float*)d_in[1];
    const float* b_in = (const float*)d_in[2];
    const float* W_r  = (const float*)d_in[3];
    const float* b_r  = (const float*)d_in[4];
    const float* W_fc = (const float*)d_in[5];
    const float* b_fc = (const float*)d_in[6];
    float* outp = (float*)d_out;
    (void)in_sizes; (void)n_in; (void)out_size; (void)d_ws; (void)ws_size;
    ltc_kernel<<<dim3(512), dim3(128), 0, stream>>>(x, W_in, b_in, W_r, b_r, W_fc, b_fc, outp);
}